// Round 1
// baseline (1202.289 us; speedup 1.0000x reference)
//
#include <hip/hip_runtime.h>

#define EPS_F   0.1f
#define INV_EPS 10.0f
#define NB 16
#define NN 512
#define ND 128
#define MAX_ITER 20
#define NEG_INF (-__builtin_inff())
// log(1/512 + 1e-8) computed in fp32 like the reference
#define LOG_MU (-6.2383195f)

__device__ __forceinline__ void lse_comb(float& m, float& s, float m2, float s2) {
    float mn = fmaxf(m, m2);
    s = s * __expf(m - mn) + s2 * __expf(m2 - mn);
    m = mn;
}

// Kernel 1: row sums of squares for x and y, plus zero-init of u, v, errAcc, cost.
// One wave per 128-elem row. 4096 blocks x 256 threads covers 16384 rows.
__global__ void k_init(const float* __restrict__ x, const float* __restrict__ y,
                       float* __restrict__ xsq, float* __restrict__ ysq,
                       float* __restrict__ uv, float* __restrict__ errAcc,
                       float* __restrict__ cost) {
    int tid = threadIdx.x;
    int w = tid >> 6, l = tid & 63;
    int row = blockIdx.x * 4 + w;                     // 0..16383
    const float* src = (row < NB * NN) ? (x + (size_t)row * ND)
                                       : (y + (size_t)(row - NB * NN) * ND);
    float a0 = src[l];
    float a1 = src[l + 64];
    float ss = a0 * a0 + a1 * a1;
#pragma unroll
    for (int off = 32; off; off >>= 1) ss += __shfl_xor(ss, off, 64);
    if (l == 0) {
        if (row < NB * NN) xsq[row] = ss;
        else               ysq[row - NB * NN] = ss;
    }
    if (blockIdx.x == 0) {
        for (int idx = tid; idx < 2 * NB * NN; idx += 256) uv[idx] = 0.0f;  // u and v
        if (tid < MAX_ITER) errAcc[tid] = 0.0f;
        if (tid < NB)       cost[tid] = 0.0f;
    }
}

// Kernel 2: C[b,i,j] = xsq[b,i] + ysq[b,j] - 2 * dot(x[b,i,:], y[b,j,:])
// 64x64 output tile per WG, K staged in halves of 64, 4x4 per-thread register tile.
// Interleaved row mapping (r16 + 16q) keeps LDS read conflicts <= 2-way.
__global__ void k_cost_matrix(const float* __restrict__ x, const float* __restrict__ y,
                              const float* __restrict__ xsq, const float* __restrict__ ysq,
                              float* __restrict__ C) {
    __shared__ float xs[64][68];
    __shared__ float ys[64][68];
    int b  = blockIdx.z;
    int i0 = blockIdx.y * 64;
    int j0 = blockIdx.x * 64;
    int tid = threadIdx.x;
    const float* xb = x + ((size_t)b * NN + i0) * ND;
    const float* yb = y + ((size_t)b * NN + j0) * ND;
    float acc[4][4] = {};
    int r16 = tid >> 4, c16 = tid & 15;
    for (int k0 = 0; k0 < ND; k0 += 64) {
#pragma unroll
        for (int it = 0; it < 4; ++it) {
            int idx = tid + 256 * it;                 // float4 index, 1024 per array
            int r  = idx >> 4;                        // 16 float4 per 64-wide k slab
            int d4 = (idx & 15) << 2;
            float4 vx = *(const float4*)(xb + (size_t)r * ND + k0 + d4);
            float4 vy = *(const float4*)(yb + (size_t)r * ND + k0 + d4);
            *(float4*)(&xs[r][d4]) = vx;
            *(float4*)(&ys[r][d4]) = vy;
        }
        __syncthreads();
#pragma unroll
        for (int k = 0; k < 64; k += 4) {
            float4 av[4], bv[4];
#pragma unroll
            for (int q = 0; q < 4; ++q) av[q] = *(const float4*)(&xs[r16 + 16 * q][k]);
#pragma unroll
            for (int p = 0; p < 4; ++p) bv[p] = *(const float4*)(&ys[c16 + 16 * p][k]);
#pragma unroll
            for (int q = 0; q < 4; ++q)
#pragma unroll
                for (int p = 0; p < 4; ++p)
                    acc[q][p] += av[q].x * bv[p].x + av[q].y * bv[p].y +
                                 av[q].z * bv[p].z + av[q].w * bv[p].w;
        }
        __syncthreads();
    }
#pragma unroll
    for (int q = 0; q < 4; ++q) {
        int i = i0 + r16 + 16 * q;
        float xq = xsq[b * NN + i];
#pragma unroll
        for (int p = 0; p < 4; ++p) {
            int j = j0 + c16 + 16 * p;
            C[((size_t)b * NN + i) * NN + j] = xq + ysq[b * NN + j] - 2.0f * acc[q][p];
        }
    }
}

// Kernel 3 (per iteration): u update. One wave per row; exact LSE via max + sum-exp
// with butterfly (m,s) combine. Accumulates sum|du| into errAcc[t].
__global__ void k_row(const float* __restrict__ C, const float* __restrict__ v,
                      float* __restrict__ u, float* __restrict__ errAcc, int t) {
    __shared__ float vs[NN];
    __shared__ float part[4];
    __shared__ int frozen_s;
    int tid = threadIdx.x;
    if (tid == 0) {
        int f = 0;
        for (int k = 0; k < t; ++k) f |= (errAcc[k] < 0.1f * NB) ? 1 : 0;
        frozen_s = f;
    }
    __syncthreads();
    if (frozen_s) return;
    int b  = blockIdx.x >> 7;                         // 128 WGs per batch
    int i0 = (blockIdx.x & 127) << 2;                 // 4 rows per WG
    vs[tid]       = v[b * NN + tid];
    vs[tid + 256] = v[b * NN + tid + 256];
    __syncthreads();
    int w = tid >> 6, l = tid & 63;
    int i = i0 + w;
    const float* Crow = C + ((size_t)b * NN + i) * NN;
    float tv[8];
#pragma unroll
    for (int k = 0; k < 8; ++k) tv[k] = (vs[l + 64 * k] - Crow[l + 64 * k]) * INV_EPS;
    float m = tv[0];
#pragma unroll
    for (int k = 1; k < 8; ++k) m = fmaxf(m, tv[k]);
    float s = 0.0f;
#pragma unroll
    for (int k = 0; k < 8; ++k) s += __expf(tv[k] - m);
#pragma unroll
    for (int off = 32; off; off >>= 1) {
        float m2 = __shfl_xor(m, off, 64);
        float s2 = __shfl_xor(s, off, 64);
        lse_comb(m, s, m2, s2);
    }
    if (l == 0) {
        float L  = m + __logf(s);
        float un = EPS_F * (LOG_MU - L);              // u_i cancels analytically
        float uo = u[b * NN + i];
        u[b * NN + i] = un;
        part[w] = fabsf(un - uo);
    }
    __syncthreads();
    if (tid == 0) atomicAdd(&errAcc[t], part[0] + part[1] + part[2] + part[3]);
}

// Kernel 4 (per iteration): v update. WG = (batch, 128-col block); 1024 threads
// split the 512 rows 8 ways per column; partial (m,s) combined in LDS.
__global__ void __launch_bounds__(1024)
k_col(const float* __restrict__ C, const float* __restrict__ u,
      float* __restrict__ v, const float* __restrict__ errAcc, int t) {
    __shared__ float us[NN];
    __shared__ float mP[8][128];
    __shared__ float sP[8][128];
    __shared__ int frozen_s;
    int tid = threadIdx.x;
    if (tid == 0) {
        int f = 0;
        for (int k = 0; k < t; ++k) f |= (errAcc[k] < 0.1f * NB) ? 1 : 0;
        frozen_s = f;
    }
    __syncthreads();
    if (frozen_s) return;
    int b  = blockIdx.x >> 2;
    int jb = blockIdx.x & 3;
    if (tid < NN) us[tid] = u[b * NN + tid];
    __syncthreads();
    int jj = tid & 127, ic = tid >> 7;
    const float* Cc = C + (size_t)b * NN * NN + (jb * 128 + jj);
    float m = NEG_INF, s = 0.0f;
    for (int i = ic * 64; i < ic * 64 + 64; i += 8) {
        float tv[8];
#pragma unroll
        for (int kk = 0; kk < 8; ++kk)
            tv[kk] = (us[i + kk] - Cc[(size_t)(i + kk) * NN]) * INV_EPS;
        float ml = tv[0];
#pragma unroll
        for (int kk = 1; kk < 8; ++kk) ml = fmaxf(ml, tv[kk]);
        float mn = fmaxf(m, ml);
        s *= __expf(m - mn);
#pragma unroll
        for (int kk = 0; kk < 8; ++kk) s += __expf(tv[kk] - mn);
        m = mn;
    }
    mP[ic][jj] = m;
    sP[ic][jj] = s;
    __syncthreads();
    if (tid < 128) {
        float mm = mP[0][tid], ss = sP[0][tid];
#pragma unroll
        for (int q = 1; q < 8; ++q) lse_comb(mm, ss, mP[q][tid], sP[q][tid]);
        float L = mm + __logf(ss);
        v[b * NN + jb * 128 + tid] = EPS_F * (LOG_MU - L);
    }
}

// Kernel 5: pi = exp((u+v-C)/eps), cost[b] = sum pi*C. One WG = 256 contiguous
// elements (half a row: b,i uniform per WG).
__global__ void k_pi(const float* __restrict__ C, const float* __restrict__ u,
                     const float* __restrict__ v, float* __restrict__ pi,
                     float* __restrict__ cost) {
    __shared__ float ps[4];
    int tid = threadIdx.x;
    size_t e = (size_t)blockIdx.x * 256 + tid;
    int b  = (int)(e >> 18);                          // 512*512 = 2^18 per batch
    int ij = (int)(e & 262143);
    int i = ij >> 9, j = ij & 511;
    float c = C[e];
    float p = __expf((u[b * NN + i] + v[b * NN + j] - c) * INV_EPS);
    pi[e] = p;
    float contrib = p * c;
#pragma unroll
    for (int off = 32; off; off >>= 1) contrib += __shfl_xor(contrib, off, 64);
    if ((tid & 63) == 0) ps[tid >> 6] = contrib;
    __syncthreads();
    if (tid == 0) atomicAdd(&cost[b], ps[0] + ps[1] + ps[2] + ps[3]);
}

extern "C" void kernel_launch(void* const* d_in, const int* in_sizes, int n_in,
                              void* d_out, int out_size, void* d_ws, size_t ws_size,
                              hipStream_t stream) {
    const float* x = (const float*)d_in[0];
    const float* y = (const float*)d_in[1];

    // Output layout: cost[16], pi[16*512*512], C[16*512*512]
    float* cost = (float*)d_out;
    float* pi   = cost + 16;
    float* C    = pi + (size_t)NB * NN * NN;

    // Workspace layout (floats): xsq[8192], ysq[8192], u[8192], v[8192], errAcc[20]
    float* f = (float*)d_ws;
    float* xsq = f;
    float* ysq = f + 8192;
    float* uv  = f + 16384;
    float* u   = uv;
    float* v   = uv + 8192;
    float* errAcc = f + 32768;

    hipLaunchKernelGGL(k_init, dim3(4096), dim3(256), 0, stream,
                       x, y, xsq, ysq, uv, errAcc, cost);
    hipLaunchKernelGGL(k_cost_matrix, dim3(8, 8, 16), dim3(256), 0, stream,
                       x, y, xsq, ysq, C);
    for (int t = 0; t < MAX_ITER; ++t) {
        hipLaunchKernelGGL(k_row, dim3(2048), dim3(256), 0, stream, C, v, u, errAcc, t);
        hipLaunchKernelGGL(k_col, dim3(64), dim3(1024), 0, stream, C, u, v, errAcc, t);
    }
    hipLaunchKernelGGL(k_pi, dim3(16384), dim3(256), 0, stream, C, u, v, pi, cost);
}

// Round 2
// 516.873 us; speedup vs baseline: 2.3261x; 2.3261x over previous
//
#include <hip/hip_runtime.h>

#define EPS_F   0.1f
#define INV_EPS 10.0f
#define NB 16
#define NN 512
#define ND 128
#define MAX_ITER 20
#define NEG_INF (-__builtin_inff())
// log(1/512 + 1e-8) computed in fp32 like the reference
#define LOG_MU (-6.2383195f)

__device__ __forceinline__ void lse_comb(float& m, float& s, float m2, float s2) {
    float mn = fmaxf(m, m2);
    s = s * __expf(m - mn) + s2 * __expf(m2 - mn);
    m = mn;
}

// Kernel 1: row sums of squares for x and y, plus zero-init of u, v, errAcc.
__global__ void k_init(const float* __restrict__ x, const float* __restrict__ y,
                       float* __restrict__ xsq, float* __restrict__ ysq,
                       float* __restrict__ uv, float* __restrict__ errAcc) {
    int tid = threadIdx.x;
    int w = tid >> 6, l = tid & 63;
    int row = blockIdx.x * 4 + w;                     // 0..16383
    const float* src = (row < NB * NN) ? (x + (size_t)row * ND)
                                       : (y + (size_t)(row - NB * NN) * ND);
    float a0 = src[l];
    float a1 = src[l + 64];
    float ss = a0 * a0 + a1 * a1;
#pragma unroll
    for (int off = 32; off; off >>= 1) ss += __shfl_xor(ss, off, 64);
    if (l == 0) {
        if (row < NB * NN) xsq[row] = ss;
        else               ysq[row - NB * NN] = ss;
    }
    if (blockIdx.x == 0) {
        for (int idx = tid; idx < 2 * NB * NN; idx += 256) uv[idx] = 0.0f;  // u and v
        if (tid < MAX_ITER) errAcc[tid] = 0.0f;
    }
}

// Kernel 2: C[b,i,j] = xsq[b,i] + ysq[b,j] - 2 * dot(x[b,i,:], y[b,j,:])
// 64x64 output tile per WG, K staged in halves of 64, 4x4 per-thread register tile.
__global__ void k_cost_matrix(const float* __restrict__ x, const float* __restrict__ y,
                              const float* __restrict__ xsq, const float* __restrict__ ysq,
                              float* __restrict__ C) {
    __shared__ float xs[64][68];
    __shared__ float ys[64][68];
    int b  = blockIdx.z;
    int i0 = blockIdx.y * 64;
    int j0 = blockIdx.x * 64;
    int tid = threadIdx.x;
    const float* xb = x + ((size_t)b * NN + i0) * ND;
    const float* yb = y + ((size_t)b * NN + j0) * ND;
    float acc[4][4] = {};
    int r16 = tid >> 4, c16 = tid & 15;
    for (int k0 = 0; k0 < ND; k0 += 64) {
#pragma unroll
        for (int it = 0; it < 4; ++it) {
            int idx = tid + 256 * it;                 // float4 index, 1024 per array
            int r  = idx >> 4;                        // 16 float4 per 64-wide k slab
            int d4 = (idx & 15) << 2;
            float4 vx = *(const float4*)(xb + (size_t)r * ND + k0 + d4);
            float4 vy = *(const float4*)(yb + (size_t)r * ND + k0 + d4);
            *(float4*)(&xs[r][d4]) = vx;
            *(float4*)(&ys[r][d4]) = vy;
        }
        __syncthreads();
#pragma unroll
        for (int k = 0; k < 64; k += 4) {
            float4 av[4], bv[4];
#pragma unroll
            for (int q = 0; q < 4; ++q) av[q] = *(const float4*)(&xs[r16 + 16 * q][k]);
#pragma unroll
            for (int p = 0; p < 4; ++p) bv[p] = *(const float4*)(&ys[c16 + 16 * p][k]);
#pragma unroll
            for (int q = 0; q < 4; ++q)
#pragma unroll
                for (int p = 0; p < 4; ++p)
                    acc[q][p] += av[q].x * bv[p].x + av[q].y * bv[p].y +
                                 av[q].z * bv[p].z + av[q].w * bv[p].w;
        }
        __syncthreads();
    }
#pragma unroll
    for (int q = 0; q < 4; ++q) {
        int i = i0 + r16 + 16 * q;
        float xq = xsq[b * NN + i];
#pragma unroll
        for (int p = 0; p < 4; ++p) {
            int j = j0 + c16 + 16 * p;
            C[((size_t)b * NN + i) * NN + j] = xq + ysq[b * NN + j] - 2.0f * acc[q][p];
        }
    }
}

// Kernel 3 (per iteration): u update. One wave per row; exact LSE via max + sum-exp
// with butterfly (m,s) combine. Writes per-block |du| partial (NO atomics).
__global__ void k_row(const float* __restrict__ C, const float* __restrict__ v,
                      float* __restrict__ u, const float* __restrict__ errAcc,
                      float* __restrict__ errPart, int t) {
    __shared__ float vs[NN];
    __shared__ float part[4];
    __shared__ int frozen_s;
    int tid = threadIdx.x;
    if (tid == 0) {
        int f = 0;
        for (int k = 0; k < t; ++k) f |= (errAcc[k] < 0.1f * NB) ? 1 : 0;
        frozen_s = f;
    }
    __syncthreads();
    if (frozen_s) return;
    int b  = blockIdx.x >> 7;                         // 128 WGs per batch
    int i0 = (blockIdx.x & 127) << 2;                 // 4 rows per WG
    vs[tid]       = v[b * NN + tid];
    vs[tid + 256] = v[b * NN + tid + 256];
    __syncthreads();
    int w = tid >> 6, l = tid & 63;
    int i = i0 + w;
    const float* Crow = C + ((size_t)b * NN + i) * NN;
    float tv[8];
#pragma unroll
    for (int k = 0; k < 8; ++k) tv[k] = (vs[l + 64 * k] - Crow[l + 64 * k]) * INV_EPS;
    float m = tv[0];
#pragma unroll
    for (int k = 1; k < 8; ++k) m = fmaxf(m, tv[k]);
    float s = 0.0f;
#pragma unroll
    for (int k = 0; k < 8; ++k) s += __expf(tv[k] - m);
#pragma unroll
    for (int off = 32; off; off >>= 1) {
        float m2 = __shfl_xor(m, off, 64);
        float s2 = __shfl_xor(s, off, 64);
        lse_comb(m, s, m2, s2);
    }
    if (l == 0) {
        float L  = m + __logf(s);
        float un = EPS_F * (LOG_MU - L);              // u_i cancels analytically
        float uo = u[b * NN + i];
        u[b * NN + i] = un;
        part[w] = fabsf(un - uo);
    }
    __syncthreads();
    if (tid == 0) errPart[blockIdx.x] = part[0] + part[1] + part[2] + part[3];
}

// Kernel 4 (per iteration): v update. WG = (batch, 128-col block); 1024 threads
// split the 512 rows 8 ways per column; partial (m,s) combined in LDS.
// Block 0 additionally reduces errPart[2048] -> errAcc[t] (replaces atomics).
__global__ void __launch_bounds__(1024)
k_col(const float* __restrict__ C, const float* __restrict__ u,
      float* __restrict__ v, float* __restrict__ errAcc,
      const float* __restrict__ errPart, int t) {
    __shared__ float us[NN];
    __shared__ float mP[8][128];
    __shared__ float sP[8][128];
    __shared__ float er[16];
    __shared__ int frozen_s;
    int tid = threadIdx.x;
    if (tid == 0) {
        int f = 0;
        for (int k = 0; k < t; ++k) f |= (errAcc[k] < 0.1f * NB) ? 1 : 0;
        frozen_s = f;
    }
    __syncthreads();
    if (frozen_s) return;

    // ---- err reduction for this iteration (block 0 only, no atomics) ----
    if (blockIdx.x == 0) {
        float e = errPart[tid] + errPart[tid + 1024];
#pragma unroll
        for (int off = 32; off; off >>= 1) e += __shfl_xor(e, off, 64);
        if ((tid & 63) == 0) er[tid >> 6] = e;
        __syncthreads();
        if (tid == 0) {
            float s = 0.0f;
#pragma unroll
            for (int q = 0; q < 16; ++q) s += er[q];
            errAcc[t] = s;
        }
    }

    int b  = blockIdx.x >> 2;
    int jb = blockIdx.x & 3;
    if (tid < NN) us[tid] = u[b * NN + tid];
    __syncthreads();
    int jj = tid & 127, ic = tid >> 7;
    const float* Cc = C + (size_t)b * NN * NN + (jb * 128 + jj);
    float m = NEG_INF, s = 0.0f;
    for (int i = ic * 64; i < ic * 64 + 64; i += 8) {
        float tv[8];
#pragma unroll
        for (int kk = 0; kk < 8; ++kk)
            tv[kk] = (us[i + kk] - Cc[(size_t)(i + kk) * NN]) * INV_EPS;
        float ml = tv[0];
#pragma unroll
        for (int kk = 1; kk < 8; ++kk) ml = fmaxf(ml, tv[kk]);
        float mn = fmaxf(m, ml);
        s *= __expf(m - mn);
#pragma unroll
        for (int kk = 0; kk < 8; ++kk) s += __expf(tv[kk] - mn);
        m = mn;
    }
    mP[ic][jj] = m;
    sP[ic][jj] = s;
    __syncthreads();
    if (tid < 128) {
        float mm = mP[0][tid], ss = sP[0][tid];
#pragma unroll
        for (int q = 1; q < 8; ++q) lse_comb(mm, ss, mP[q][tid], sP[q][tid]);
        float L = mm + __logf(ss);
        v[b * NN + jb * 128 + tid] = EPS_F * (LOG_MU - L);
    }
}

// Kernel 5: pi = exp((u+v-C)/eps); per-block partial of pi*C -> costPart (no atomics).
__global__ void k_pi(const float* __restrict__ C, const float* __restrict__ u,
                     const float* __restrict__ v, float* __restrict__ pi,
                     float* __restrict__ costPart) {
    __shared__ float ps[4];
    int tid = threadIdx.x;
    size_t e = (size_t)blockIdx.x * 256 + tid;
    int b  = (int)(e >> 18);                          // 512*512 = 2^18 per batch
    int ij = (int)(e & 262143);
    int i = ij >> 9, j = ij & 511;
    float c = C[e];
    float p = __expf((u[b * NN + i] + v[b * NN + j] - c) * INV_EPS);
    pi[e] = p;
    float contrib = p * c;
#pragma unroll
    for (int off = 32; off; off >>= 1) contrib += __shfl_xor(contrib, off, 64);
    if ((tid & 63) == 0) ps[tid >> 6] = contrib;
    __syncthreads();
    if (tid == 0) costPart[blockIdx.x] = ps[0] + ps[1] + ps[2] + ps[3];
}

// Kernel 6: cost[b] = sum of 1024 contiguous partials per batch.
__global__ void __launch_bounds__(1024)
k_costred(const float* __restrict__ costPart, float* __restrict__ cost) {
    __shared__ float er[16];
    int b = blockIdx.x, tid = threadIdx.x;
    float s = costPart[b * 1024 + tid];
#pragma unroll
    for (int off = 32; off; off >>= 1) s += __shfl_xor(s, off, 64);
    if ((tid & 63) == 0) er[tid >> 6] = s;
    __syncthreads();
    if (tid == 0) {
        float t = 0.0f;
#pragma unroll
        for (int q = 0; q < 16; ++q) t += er[q];
        cost[b] = t;
    }
}

extern "C" void kernel_launch(void* const* d_in, const int* in_sizes, int n_in,
                              void* d_out, int out_size, void* d_ws, size_t ws_size,
                              hipStream_t stream) {
    const float* x = (const float*)d_in[0];
    const float* y = (const float*)d_in[1];

    // Output layout: cost[16], pi[16*512*512], C[16*512*512]
    float* cost = (float*)d_out;
    float* pi   = cost + 16;
    float* C    = pi + (size_t)NB * NN * NN;

    // Workspace (floats):
    //   [0..16383]      xsq(8192)+ysq(8192); reused as costPart(16384) after GEMM
    //   [16384..24575]  u
    //   [24576..32767]  v
    //   [32768..32799]  errAcc (20 used)
    //   [32800..34847]  errPart (2048)
    float* f = (float*)d_ws;
    float* xsq      = f;
    float* ysq      = f + 8192;
    float* costPart = f;                // reuse: xsq/ysq dead after k_cost_matrix
    float* uv       = f + 16384;
    float* u        = uv;
    float* v        = uv + 8192;
    float* errAcc   = f + 32768;
    float* errPart  = f + 32800;

    hipLaunchKernelGGL(k_init, dim3(4096), dim3(256), 0, stream,
                       x, y, xsq, ysq, uv, errAcc);
    hipLaunchKernelGGL(k_cost_matrix, dim3(8, 8, 16), dim3(256), 0, stream,
                       x, y, xsq, ysq, C);
    for (int t = 0; t < MAX_ITER; ++t) {
        hipLaunchKernelGGL(k_row, dim3(2048), dim3(256), 0, stream,
                           C, v, u, errAcc, errPart, t);
        hipLaunchKernelGGL(k_col, dim3(64), dim3(1024), 0, stream,
                           C, u, v, errAcc, errPart, t);
    }
    hipLaunchKernelGGL(k_pi, dim3(16384), dim3(256), 0, stream, C, u, v, pi, costPart);
    hipLaunchKernelGGL(k_costred, dim3(16), dim3(1024), 0, stream, costPart, cost);
}

// Round 3
// 327.997 us; speedup vs baseline: 3.6656x; 1.5758x over previous
//
#include <hip/hip_runtime.h>

#define EPS_F   0.1f
#define INV_EPS 10.0f
#define NB 16
#define NN 512
#define ND 128
#define MAX_ITER 20
#define NEG_INF (-__builtin_inff())
// log(1/512 + 1e-8) computed in fp32 like the reference
#define LOG_MU (-6.2383195f)

// All grids use bid = 16*t + b so that bid % 8 == b % 8: with round-robin
// block->XCD dispatch, every block touching batch b lands on XCD b%8.
// Each XCD then serves 2 batches (~2 MB of C) out of its 4 MB L2, so the
// 40 iteration passes over C are L2-resident instead of HBM/MALL traffic.

__device__ __forceinline__ void lse_comb(float& m, float& s, float m2, float s2) {
    float mn = fmaxf(m, m2);
    s = s * __expf(m - mn) + s2 * __expf(m2 - mn);
    m = mn;
}

__device__ __forceinline__ int frozen_check(const float* errAcc, int t) {
    int f = 0;
    for (int k = 0; k < t; ++k) f |= (errAcc[k] < 0.1f * NB) ? 1 : 0;
    return f;
}

// Kernel 1: row sums of squares for x and y, plus zero-init of u, v, errAcc.
// Grid 4096 = 16 batches x 256 tiles; t<128 -> x rows, else y rows.
__global__ void k_init(const float* __restrict__ x, const float* __restrict__ y,
                       float* __restrict__ xsq, float* __restrict__ ysq,
                       float* __restrict__ uv, float* __restrict__ errAcc) {
    int tid = threadIdx.x;
    int w = tid >> 6, l = tid & 63;
    int b = blockIdx.x & 15;
    int t = blockIdx.x >> 4;                          // 0..255
    int isY = (t >= 128);
    int i = (isY ? (t - 128) : t) * 4 + w;            // row within batch
    const float* src = (isY ? y : x) + ((size_t)b * NN + i) * ND;
    float a0 = src[l];
    float a1 = src[l + 64];
    float ss = a0 * a0 + a1 * a1;
#pragma unroll
    for (int off = 32; off; off >>= 1) ss += __shfl_xor(ss, off, 64);
    if (l == 0) {
        if (isY) ysq[b * NN + i] = ss;
        else     xsq[b * NN + i] = ss;
    }
    if (blockIdx.x == 0) {
        for (int idx = tid; idx < 2 * NB * NN; idx += 256) uv[idx] = 0.0f;  // u and v
        if (tid < MAX_ITER) errAcc[tid] = 0.0f;
    }
}

// Kernel 2: C[b,i,j] = xsq[b,i] + ysq[b,j] - 2 * dot(x[b,i],y[b,j])
// 128x128 tile per WG (grid 256 = 1 block/CU), 256 threads, 8x8 per thread.
// LDS holds K-transposed slabs As[k][row] so A/B fragments are float4 reads.
// Epilogue stores float4 per lane -> each wave writes 4 x 256 B full runs.
#define BK 32
#define LS 132                                        // LDS row stride (pad 4)
__global__ __launch_bounds__(256) void
k_cost(const float* __restrict__ x, const float* __restrict__ y,
       const float* __restrict__ xsq, const float* __restrict__ ysq,
       float* __restrict__ C) {
    __shared__ float As[BK][LS];
    __shared__ float Bs[BK][LS];
    int bid = blockIdx.x;
    int b = bid & 15;
    int t = bid >> 4;                                 // 0..15
    int i0 = (t >> 2) * 128;
    int j0 = (t & 3) * 128;
    int tid = threadIdx.x;
    int tx = tid & 15, ty = tid >> 4;
    const float* xb = x + ((size_t)b * NN + i0) * ND;
    const float* yb = y + ((size_t)b * NN + j0) * ND;
    float acc[8][8] = {};
    for (int k0 = 0; k0 < ND; k0 += BK) {
        __syncthreads();                              // protect LDS reuse
#pragma unroll
        for (int it = 0; it < 4; ++it) {
            int idx = tid + 256 * it;                 // 1024 float4 per array
            int r  = idx >> 3;                        // 0..127
            int kq = (idx & 7) << 2;                  // 0,4,..,28
            float4 vx = *(const float4*)(xb + (size_t)r * ND + k0 + kq);
            float4 vy = *(const float4*)(yb + (size_t)r * ND + k0 + kq);
            As[kq + 0][r] = vx.x; As[kq + 1][r] = vx.y;
            As[kq + 2][r] = vx.z; As[kq + 3][r] = vx.w;
            Bs[kq + 0][r] = vy.x; Bs[kq + 1][r] = vy.y;
            Bs[kq + 2][r] = vy.z; Bs[kq + 3][r] = vy.w;
        }
        __syncthreads();
#pragma unroll
        for (int k = 0; k < BK; ++k) {
            float4 a0 = *(const float4*)&As[k][ty * 4];
            float4 a1 = *(const float4*)&As[k][64 + ty * 4];
            float4 b0 = *(const float4*)&Bs[k][tx * 4];
            float4 b1 = *(const float4*)&Bs[k][64 + tx * 4];
            float ar[8] = {a0.x, a0.y, a0.z, a0.w, a1.x, a1.y, a1.z, a1.w};
            float br[8] = {b0.x, b0.y, b0.z, b0.w, b1.x, b1.y, b1.z, b1.w};
#pragma unroll
            for (int q = 0; q < 8; ++q)
#pragma unroll
                for (int p = 0; p < 8; ++p) acc[q][p] += ar[q] * br[p];
        }
    }
    float ys8[8], xs8[8];
#pragma unroll
    for (int g = 0; g < 2; ++g)
#pragma unroll
        for (int p = 0; p < 4; ++p)
            ys8[g * 4 + p] = ysq[b * NN + j0 + 64 * g + tx * 4 + p];
#pragma unroll
    for (int h = 0; h < 2; ++h)
#pragma unroll
        for (int q = 0; q < 4; ++q)
            xs8[h * 4 + q] = xsq[b * NN + i0 + 64 * h + ty * 4 + q];
#pragma unroll
    for (int h = 0; h < 2; ++h) {
#pragma unroll
        for (int q = 0; q < 4; ++q) {
            int i = i0 + 64 * h + ty * 4 + q;
            float xq = xs8[h * 4 + q];
            float* Crow = C + ((size_t)b * NN + i) * NN + j0;
#pragma unroll
            for (int g = 0; g < 2; ++g) {
                float4 out;
                out.x = xq + ys8[g * 4 + 0] - 2.0f * acc[h * 4 + q][g * 4 + 0];
                out.y = xq + ys8[g * 4 + 1] - 2.0f * acc[h * 4 + q][g * 4 + 1];
                out.z = xq + ys8[g * 4 + 2] - 2.0f * acc[h * 4 + q][g * 4 + 2];
                out.w = xq + ys8[g * 4 + 3] - 2.0f * acc[h * 4 + q][g * 4 + 3];
                *(float4*)(Crow + 64 * g + tx * 4) = out;
            }
        }
    }
}

// Kernel 3 (per iteration): u update. One wave per row, float4 C loads.
// Grid 2048 = 16 batches x 128 blocks (4 rows each).
__global__ __launch_bounds__(256) void
k_row(const float* __restrict__ C, const float* __restrict__ v,
      float* __restrict__ u, const float* __restrict__ errAcc,
      float* __restrict__ errPart, int t) {
    __shared__ float vs[NN];
    __shared__ float part[4];
    __shared__ int frozen_s;
    int tid = threadIdx.x;
    int b  = blockIdx.x & 15;
    int i0 = (blockIdx.x >> 4) << 2;                  // 4 rows per WG
    if (tid == 0) frozen_s = frozen_check(errAcc, t);
    vs[tid]       = v[b * NN + tid];
    vs[tid + 256] = v[b * NN + tid + 256];
    __syncthreads();
    if (frozen_s) return;
    int w = tid >> 6, l = tid & 63;
    int i = i0 + w;
    const float* Crow = C + ((size_t)b * NN + i) * NN;
    float4 c0 = *(const float4*)(Crow + 4 * l);
    float4 c1 = *(const float4*)(Crow + 256 + 4 * l);
    float4 v0 = *(const float4*)(vs + 4 * l);
    float4 v1 = *(const float4*)(vs + 256 + 4 * l);
    float tv[8] = {(v0.x - c0.x) * INV_EPS, (v0.y - c0.y) * INV_EPS,
                   (v0.z - c0.z) * INV_EPS, (v0.w - c0.w) * INV_EPS,
                   (v1.x - c1.x) * INV_EPS, (v1.y - c1.y) * INV_EPS,
                   (v1.z - c1.z) * INV_EPS, (v1.w - c1.w) * INV_EPS};
    float m = tv[0];
#pragma unroll
    for (int k = 1; k < 8; ++k) m = fmaxf(m, tv[k]);
    float s = 0.0f;
#pragma unroll
    for (int k = 0; k < 8; ++k) s += __expf(tv[k] - m);
#pragma unroll
    for (int off = 32; off; off >>= 1) {
        float m2 = __shfl_xor(m, off, 64);
        float s2 = __shfl_xor(s, off, 64);
        lse_comb(m, s, m2, s2);
    }
    if (l == 0) {
        float L  = m + __logf(s);
        float un = EPS_F * (LOG_MU - L);              // u_i cancels analytically
        float uo = u[b * NN + i];
        u[b * NN + i] = un;
        part[w] = fabsf(un - uo);
    }
    __syncthreads();
    if (tid == 0) errPart[blockIdx.x] = part[0] + part[1] + part[2] + part[3];
}

// Kernel 4 (per iteration): v update. Grid 64 = 16 batches x 4 col-blocks.
// Block 0 additionally reduces errPart[2048] -> errAcc[t].
__global__ void __launch_bounds__(1024)
k_col(const float* __restrict__ C, const float* __restrict__ u,
      float* __restrict__ v, float* __restrict__ errAcc,
      const float* __restrict__ errPart, int t) {
    __shared__ float us[NN];
    __shared__ float mP[8][128];
    __shared__ float sP[8][128];
    __shared__ float er[16];
    __shared__ int frozen_s;
    int tid = threadIdx.x;
    if (tid == 0) frozen_s = frozen_check(errAcc, t);
    __syncthreads();
    if (frozen_s) return;

    if (blockIdx.x == 0) {                            // err reduction, no atomics
        float e = errPart[tid] + errPart[tid + 1024];
#pragma unroll
        for (int off = 32; off; off >>= 1) e += __shfl_xor(e, off, 64);
        if ((tid & 63) == 0) er[tid >> 6] = e;
        __syncthreads();
        if (tid == 0) {
            float s = 0.0f;
#pragma unroll
            for (int q = 0; q < 16; ++q) s += er[q];
            errAcc[t] = s;
        }
    }

    int b  = blockIdx.x & 15;
    int jb = blockIdx.x >> 4;                         // 0..3
    if (tid < NN) us[tid] = u[b * NN + tid];
    __syncthreads();
    int jj = tid & 127, ic = tid >> 7;
    const float* Cc = C + (size_t)b * NN * NN + (jb * 128 + jj);
    float m = NEG_INF, s = 0.0f;
    for (int i = ic * 64; i < ic * 64 + 64; i += 8) {
        float tv[8];
#pragma unroll
        for (int kk = 0; kk < 8; ++kk)
            tv[kk] = (us[i + kk] - Cc[(size_t)(i + kk) * NN]) * INV_EPS;
        float ml = tv[0];
#pragma unroll
        for (int kk = 1; kk < 8; ++kk) ml = fmaxf(ml, tv[kk]);
        float mn = fmaxf(m, ml);
        s *= __expf(m - mn);
#pragma unroll
        for (int kk = 0; kk < 8; ++kk) s += __expf(tv[kk] - mn);
        m = mn;
    }
    mP[ic][jj] = m;
    sP[ic][jj] = s;
    __syncthreads();
    if (tid < 128) {
        float mm = mP[0][tid], ss = sP[0][tid];
#pragma unroll
        for (int q = 1; q < 8; ++q) lse_comb(mm, ss, mP[q][tid], sP[q][tid]);
        float L = mm + __logf(ss);
        v[b * NN + jb * 128 + tid] = EPS_F * (LOG_MU - L);
    }
}

// Kernel 5: pi = exp((u+v-C)/eps); float4 per lane; per-block partial -> costPart.
// Grid 4096 = 16 batches x 256 tiles of 1024 elements.
__global__ __launch_bounds__(256) void
k_pi(const float* __restrict__ C, const float* __restrict__ u,
     const float* __restrict__ v, float* __restrict__ pi,
     float* __restrict__ costPart) {
    __shared__ float ps[4];
    int tid = threadIdx.x;
    int b = blockIdx.x & 15;
    int t = blockIdx.x >> 4;                          // 0..255
    size_t e = ((size_t)b << 18) + (size_t)t * 1024 + tid * 4;
    int ij = (int)(e & 262143);
    int i = ij >> 9, j = ij & 511;                    // j..j+3 same row (4-aligned)
    float4 c4 = *(const float4*)(C + e);
    float4 v4 = *(const float4*)(v + b * NN + j);
    float uu = u[b * NN + i];
    float4 p4;
    p4.x = __expf((uu + v4.x - c4.x) * INV_EPS);
    p4.y = __expf((uu + v4.y - c4.y) * INV_EPS);
    p4.z = __expf((uu + v4.z - c4.z) * INV_EPS);
    p4.w = __expf((uu + v4.w - c4.w) * INV_EPS);
    *(float4*)(pi + e) = p4;
    float contrib = p4.x * c4.x + p4.y * c4.y + p4.z * c4.z + p4.w * c4.w;
#pragma unroll
    for (int off = 32; off; off >>= 1) contrib += __shfl_xor(contrib, off, 64);
    if ((tid & 63) == 0) ps[tid >> 6] = contrib;
    __syncthreads();
    if (tid == 0) costPart[blockIdx.x] = ps[0] + ps[1] + ps[2] + ps[3];
}

// Kernel 6: cost[b] = sum of 256 partials (strided by 16 in costPart).
__global__ __launch_bounds__(256) void
k_costred(const float* __restrict__ costPart, float* __restrict__ cost) {
    __shared__ float er[4];
    int b = blockIdx.x, tid = threadIdx.x;
    float s = costPart[tid * 16 + b];
#pragma unroll
    for (int off = 32; off; off >>= 1) s += __shfl_xor(s, off, 64);
    if ((tid & 63) == 0) er[tid >> 6] = s;
    __syncthreads();
    if (tid == 0) cost[b] = er[0] + er[1] + er[2] + er[3];
}

extern "C" void kernel_launch(void* const* d_in, const int* in_sizes, int n_in,
                              void* d_out, int out_size, void* d_ws, size_t ws_size,
                              hipStream_t stream) {
    const float* x = (const float*)d_in[0];
    const float* y = (const float*)d_in[1];

    // Output layout: cost[16], pi[16*512*512], C[16*512*512]
    float* cost = (float*)d_out;
    float* pi   = cost + 16;
    float* C    = pi + (size_t)NB * NN * NN;

    // Workspace (floats):
    //   [0..16383]      xsq(8192)+ysq(8192); reused as costPart(4096) after GEMM
    //   [16384..24575]  u
    //   [24576..32767]  v
    //   [32768..32799]  errAcc (20 used)
    //   [32800..34847]  errPart (2048)
    float* f = (float*)d_ws;
    float* xsq      = f;
    float* ysq      = f + 8192;
    float* costPart = f;                // reuse: xsq/ysq dead after k_cost
    float* uv       = f + 16384;
    float* u        = uv;
    float* v        = uv + 8192;
    float* errAcc   = f + 32768;
    float* errPart  = f + 32800;

    hipLaunchKernelGGL(k_init, dim3(4096), dim3(256), 0, stream,
                       x, y, xsq, ysq, uv, errAcc);
    hipLaunchKernelGGL(k_cost, dim3(256), dim3(256), 0, stream,
                       x, y, xsq, ysq, C);
    for (int t = 0; t < MAX_ITER; ++t) {
        hipLaunchKernelGGL(k_row, dim3(2048), dim3(256), 0, stream,
                           C, v, u, errAcc, errPart, t);
        hipLaunchKernelGGL(k_col, dim3(64), dim3(1024), 0, stream,
                           C, u, v, errAcc, errPart, t);
    }
    hipLaunchKernelGGL(k_pi, dim3(4096), dim3(256), 0, stream, C, u, v, pi, costPart);
    hipLaunchKernelGGL(k_costred, dim3(16), dim3(256), 0, stream, costPart, cost);
}